// Round 4
// baseline (1016.734 us; speedup 1.0000x reference)
//
#include <hip/hip_runtime.h>

// DHPM fused forward v4 (MI355X / gfx950).
// vs v3: each wave computes ALL 6 channels for its own 32 points (2 mtiles,
// sin+cos A-frags resident) -> 12 MFMAs per 6 B-reads, no cross-group
// exchange (in-lane epilogue), 256 pts/block, ping-pong B staging with one
// barrier per j-tile, coalesced final store via LDS res buffer.

#define HID 200
#define NPTS 256
#define NTHREADS 512
#define NT 13
#define KT 7
#define BLDK 232          // f16 row stride (464 B = 29 granules -> 2-way, free)
#define BCHUNK 45056
#define FCHUNK 8192

#define OFF_U  0
#define OFF_V  585728     // 13*45056
#define OFF_F  1171456    // 2*13*45056
#define OFF_CU 1277952
#define OFF_CV 1281152
#define OFF_CF 1284352

typedef _Float16 f16;
typedef _Float16 f16x2 __attribute__((ext_vector_type(2)));
typedef _Float16 f16x8 __attribute__((ext_vector_type(8)));
typedef float f32x4 __attribute__((ext_vector_type(4)));

#define GLDS16(gp, lp) __builtin_amdgcn_global_load_lds( \
    (const __attribute__((address_space(1))) void*)(gp), \
    (__attribute__((address_space(3))) void*)(lp), 16, 0, 0)

__global__ __launch_bounds__(256) void dhpm_prep(
    const float* __restrict__ Wu0, const float* __restrict__ bu0, const float* __restrict__ Wu1,
    const float* __restrict__ Wv0, const float* __restrict__ bv0, const float* __restrict__ Wv1,
    const float* __restrict__ Wf0, const float* __restrict__ bf0, const float* __restrict__ Wf1,
    char* __restrict__ ws)
{
    const int id = blockIdx.x * blockDim.x + threadIdx.x;
    const int nB = 2 * NT * 96 * 116;   // 289536
    const int nF = NT * 16 * 116;       // 24128
    if (id < nB) {
        int e = id;
        const int net = e / (NT*96*116); e -= net * (NT*96*116);
        const int nt  = e / (96*116);    e -= nt * (96*116);
        const int row = e / 116;
        const int k2  = e - row*116;
        const int ch  = row >> 4;
        const int j   = nt*16 + (row & 15);
        const int k   = k2*2;
        const float* W0 = net ? Wv0 : Wu0;
        const float* W1 = net ? Wv1 : Wu1;
        f16x2 v; v[0] = (f16)0.f; v[1] = (f16)0.f;
        if (j < HID) {
            #pragma unroll
            for (int s = 0; s < 2; ++s) {
                const int ks = k + s;
                if (ks < HID) {
                    const float w1 = W1[j*HID + ks];
                    const float ax = W0[ks*3+0], ay = W0[ks*3+1], at = W0[ks*3+2];
                    float gg;
                    if      (ch == 0) gg = 1.f;
                    else if (ch == 1) gg = -ax*ax;
                    else if (ch == 2) gg = -ay*ay;
                    else if (ch == 3) gg = ax;
                    else if (ch == 4) gg = ay;
                    else              gg = at;
                    v[s] = (f16)(w1 * gg);
                }
            }
        }
        *(f16x2*)(ws + (net ? OFF_V : OFF_U) + nt*BCHUNK + row*464 + k2*4) = v;
        return;
    }
    if (id < nB + nF) {
        int e = id - nB;
        const int nt  = e / (16*116);  e -= nt * (16*116);
        const int row = e / 116;
        const int k2  = e - row*116;
        const int j   = nt*16 + row;
        const int k   = k2*2;
        f16x2 v; v[0] = (f16)0.f; v[1] = (f16)0.f;
        if (j < HID) {
            if (k     < HID) v[0] = (f16)Wf1[j*HID + k];
            if (k + 1 < HID) v[1] = (f16)Wf1[j*HID + k + 1];
        }
        *(f16x2*)(ws + OFF_F + nt*FCHUNK + row*464 + k2*4) = v;
        return;
    }
    if (id < nB + nF + 400) {
        const int e = id - nB - nF;
        const int net = e / HID;
        const int r   = e - net*HID;
        const float* W0 = net ? Wv0 : Wu0;
        const float* b0 = net ? bv0 : bu0;
        float4 c;
        c.x = W0[r*3+0]; c.y = W0[r*3+1]; c.z = W0[r*3+2]; c.w = b0[r];
        *(float4*)(ws + (net ? OFF_CV : OFF_CU) + r*16) = c;
        return;
    }
    if (id < nB + nF + 400 + HID) {
        const int i = id - nB - nF - 400;
        float4 c0, c1, c2, c3;
        c0.x = Wf0[i*12+0];  c0.y = Wf0[i*12+1];  c0.z = Wf0[i*12+2];  c0.w = Wf0[i*12+3];
        c1.x = Wf0[i*12+4];  c1.y = Wf0[i*12+5];  c1.z = Wf0[i*12+6];  c1.w = Wf0[i*12+7];
        c2.x = Wf0[i*12+8];  c2.y = Wf0[i*12+9];  c2.z = Wf0[i*12+10]; c2.w = Wf0[i*12+11];
        c3.x = bf0[i]; c3.y = 0.f; c3.z = 0.f; c3.w = 0.f;
        char* p = ws + OFF_CF + i*64;
        *(float4*)(p)      = c0;
        *(float4*)(p + 16) = c1;
        *(float4*)(p + 32) = c2;
        *(float4*)(p + 48) = c3;
    }
}

__device__ __forceinline__ f32x4 mfma16(f16x8 a, f16x8 b, f32x4 c) {
    return __builtin_amdgcn_mfma_f32_16x16x32_f16(a, b, c, 0, 0, 0);
}

__device__ __forceinline__ void run_net(
    const float* __restrict__ inp, const char* __restrict__ ws,
    const int cstOff, const int bOff,
    const float* __restrict__ b1, const float* __restrict__ W2, const float b2s,
    const int cV, const int cXX, const int cYY,
    const int cX, const int cY, const int cT,
    char* __restrict__ Bb0, char* __restrict__ Bb1, float* __restrict__ res,
    const int gp0)
{
    const int t = threadIdx.x;
    const int lane = t & 63;
    const int w = __builtin_amdgcn_readfirstlane(t >> 6);
    const int jl = lane & 15, klo = lane >> 4;
    const int o = w * 32;
    const char* bsrc = ws + bOff;

    // stage nt=0 -> Bb0 (overlaps A-build)
    for (int c = w; c < 44; c += 8)
        GLDS16(bsrc + c*1024 + lane*16, Bb0 + c*1024);

    // ---- sin & cos A-fragments, register resident ----
    f16x8 aS[2][KT], aC[2][KT];
    {
        const float4* cst = (const float4*)(ws + cstOff);
        #pragma unroll
        for (int mt = 0; mt < 2; ++mt) {
            const int prow = gp0 + o + mt*16 + jl;
            const float x = inp[prow*3+0], y = inp[prow*3+1], tt = inp[prow*3+2];
            #pragma unroll
            for (int kt = 0; kt < KT; ++kt) {
                f16x8 fs, fc;
                #pragma unroll
                for (int e = 0; e < 8; ++e) {
                    const int i = kt*32 + klo*8 + e;
                    const float4 c = cst[(i < HID) ? i : 0];   // pad k hits zero B'
                    const float z = fmaf(c.x, x, fmaf(c.y, y, fmaf(c.z, tt, c.w)));
                    float sv, cv;
                    __sincosf(z, &sv, &cv);
                    fs[e] = (f16)sv; fc[e] = (f16)cv;
                }
                aS[mt][kt] = fs; aC[mt][kt] = fc;
            }
        }
    }

    float pV[2][4], pXX[2][4], pYY[2][4], pX[2][4], pY[2][4], pT[2][4];
    #pragma unroll
    for (int mt = 0; mt < 2; ++mt)
        #pragma unroll
        for (int r = 0; r < 4; ++r) {
            pV[mt][r]=0.f; pXX[mt][r]=0.f; pYY[mt][r]=0.f;
            pX[mt][r]=0.f; pY[mt][r]=0.f; pT[mt][r]=0.f;
        }

    __syncthreads();   // Bb0 landed (implicit vmcnt drain before barrier)

    auto step = [&](const char* Bcur, char* Bnext, const int nt, const int ntNext) {
        if (ntNext < NT)   // prefetch next tile into the other buffer
            for (int c = w; c < 44; c += 8)
                GLDS16(bsrc + ntNext*BCHUNK + c*1024 + lane*16, Bnext + c*1024);

        const f16* BH = (const f16*)Bcur;
        f32x4 acc[6][2];
        #pragma unroll
        for (int c = 0; c < 6; ++c)
            #pragma unroll
            for (int mt = 0; mt < 2; ++mt) {
                f32x4 z = {0.f,0.f,0.f,0.f};
                acc[c][mt] = z;
            }
        #pragma unroll
        for (int kt = 0; kt < KT; ++kt) {
            f16x8 bfr[6];
            #pragma unroll
            for (int c = 0; c < 6; ++c)
                bfr[c] = *(const f16x8*)&BH[(c*16 + jl)*BLDK + kt*32 + klo*8];
            #pragma unroll
            for (int c = 0; c < 3; ++c) {
                acc[c][0] = mfma16(aS[0][kt], bfr[c], acc[c][0]);
                acc[c][1] = mfma16(aS[1][kt], bfr[c], acc[c][1]);
            }
            #pragma unroll
            for (int c = 3; c < 6; ++c) {
                acc[c][0] = mfma16(aC[0][kt], bfr[c], acc[c][0]);
                acc[c][1] = mfma16(aC[1][kt], bfr[c], acc[c][1]);
            }
        }

        // ---- in-lane epilogue: lane owns (j=jl, pts klo*4+r) with all 6 Y ----
        const int j = nt*16 + jl;
        const float b1j = (j < HID) ? b1[j] : 0.f;
        const float w2j = (j < HID) ? W2[j] : 0.f;   // 0 kills pad-j
        #pragma unroll
        for (int mt = 0; mt < 2; ++mt)
            #pragma unroll
            for (int r = 0; r < 4; ++r) {
                float s1, c1;
                __sincosf(acc[0][mt][r] + b1j, &s1, &c1);
                const float wc = w2j*c1, wsn = w2j*s1;
                const float ydx = acc[3][mt][r], ydy = acc[4][mt][r];
                pV[mt][r]  += wsn;
                pXX[mt][r] = fmaf(wc, acc[1][mt][r], fmaf(-wsn*ydx, ydx, pXX[mt][r]));
                pYY[mt][r] = fmaf(wc, acc[2][mt][r], fmaf(-wsn*ydy, ydy, pYY[mt][r]));
                pX[mt][r]  = fmaf(wc, ydx, pX[mt][r]);
                pY[mt][r]  = fmaf(wc, ydy, pY[mt][r]);
                pT[mt][r]  = fmaf(wc, acc[5][mt][r], pT[mt][r]);
            }
        __syncthreads();   // all reads of Bcur done; Bnext landed
    };

    #pragma unroll
    for (int ntp = 0; ntp < 6; ++ntp) {
        step(Bb0, Bb1, ntp*2,     ntp*2 + 1);
        step(Bb1, Bb0, ntp*2 + 1, ntp*2 + 2);
    }
    step(Bb0, Bb1, 12, NT);   // last tile, no prefetch

    // ---- butterfly over the 16 j-lanes ----
    #pragma unroll
    for (int d = 1; d < 16; d <<= 1)
        #pragma unroll
        for (int mt = 0; mt < 2; ++mt)
            #pragma unroll
            for (int r = 0; r < 4; ++r) {
                pV[mt][r]  += __shfl_xor(pV[mt][r],  d);
                pXX[mt][r] += __shfl_xor(pXX[mt][r], d);
                pYY[mt][r] += __shfl_xor(pYY[mt][r], d);
                pX[mt][r]  += __shfl_xor(pX[mt][r],  d);
                pY[mt][r]  += __shfl_xor(pY[mt][r],  d);
                pT[mt][r]  += __shfl_xor(pT[mt][r],  d);
            }
    if (jl == 0) {
        #pragma unroll
        for (int mt = 0; mt < 2; ++mt) {
            const int p0 = o + mt*16 + klo*4;
            f32x4 vv;
            #pragma unroll
            for (int r = 0; r < 4; ++r) vv[r] = pV[mt][r] + b2s;
            *(f32x4*)&res[cV*264 + p0] = vv;
            #pragma unroll
            for (int r = 0; r < 4; ++r) vv[r] = pXX[mt][r];
            *(f32x4*)&res[cXX*264 + p0] = vv;
            #pragma unroll
            for (int r = 0; r < 4; ++r) vv[r] = pYY[mt][r];
            *(f32x4*)&res[cYY*264 + p0] = vv;
            #pragma unroll
            for (int r = 0; r < 4; ++r) vv[r] = pX[mt][r];
            *(f32x4*)&res[cX*264 + p0] = vv;
            #pragma unroll
            for (int r = 0; r < 4; ++r) vv[r] = pY[mt][r];
            *(f32x4*)&res[cY*264 + p0] = vv;
            #pragma unroll
            for (int r = 0; r < 4; ++r) vv[r] = pT[mt][r];
            *(f32x4*)&res[cT*264 + p0] = vv;
        }
    }
}

__global__ __launch_bounds__(NTHREADS, 2) void dhpm_main(
    const float* __restrict__ inp, const char* __restrict__ ws,
    const float* __restrict__ bu1, const float* __restrict__ Wu2, const float* __restrict__ bu2,
    const float* __restrict__ bv1, const float* __restrict__ Wv2, const float* __restrict__ bv2,
    const float* __restrict__ bf1, const float* __restrict__ Wf2, const float* __restrict__ bf2,
    float* __restrict__ out, const int Np)
{
    __shared__ __align__(16) char Bb0[BCHUNK];
    __shared__ __align__(16) char Bb1[BCHUNK];
    __shared__ __align__(16) float res[14*264];   // 14784 B

    const int t = threadIdx.x;
    const int lane = t & 63;
    const int w = __builtin_amdgcn_readfirstlane(t >> 6);
    const int jl = lane & 15, klo = lane >> 4;
    const int o = w * 32;
    const int gp0 = blockIdx.x * NPTS;

    run_net(inp, ws, OFF_CU, OFF_U, bu1, Wu2, bu2[0], 0, 5, 7, 4, 6, 2,
            Bb0, Bb1, res, gp0);
    run_net(inp, ws, OFF_CV, OFF_V, bv1, Wv2, bv2[0], 1, 9, 11, 8, 10, 3,
            Bb0, Bb1, res, gp0);

    // ======================= f-net =======================
    for (int c = w; c < 8; c += 8)
        GLDS16(ws + OFF_F + c*1024 + lane*16, Bb0 + c*1024);
    __syncthreads();   // res cols 0..11 complete + f tile 0 landed

    f16x8 aF[2][KT];
    {
        const float4* cf = (const float4*)(ws + OFF_CF);
        #pragma unroll
        for (int mt = 0; mt < 2; ++mt) {
            const int p = o + mt*16 + jl;
            float fv[12];
            #pragma unroll
            for (int k = 0; k < 12; ++k) fv[k] = res[k*264 + p];
            #pragma unroll
            for (int kt = 0; kt < KT; ++kt) {
                f16x8 f;
                #pragma unroll
                for (int e = 0; e < 8; ++e) {
                    const int i = kt*32 + klo*8 + e;
                    const int ic = (i < HID) ? i : 0;
                    const float4 c0 = cf[ic*4+0];
                    const float4 c1 = cf[ic*4+1];
                    const float4 c2 = cf[ic*4+2];
                    const float4 c3 = cf[ic*4+3];
                    float z = c3.x;
                    z = fmaf(c0.x, fv[0], z);  z = fmaf(c0.y, fv[1], z);
                    z = fmaf(c0.z, fv[2], z);  z = fmaf(c0.w, fv[3], z);
                    z = fmaf(c1.x, fv[4], z);  z = fmaf(c1.y, fv[5], z);
                    z = fmaf(c1.z, fv[6], z);  z = fmaf(c1.w, fv[7], z);
                    z = fmaf(c2.x, fv[8], z);  z = fmaf(c2.y, fv[9], z);
                    z = fmaf(c2.z, fv[10], z); z = fmaf(c2.w, fv[11], z);
                    f[e] = (f16)__sinf(z);
                }
                aF[mt][kt] = f;
            }
        }
    }

    float pf0[2][4], pf1[2][4];
    #pragma unroll
    for (int mt = 0; mt < 2; ++mt)
        #pragma unroll
        for (int r = 0; r < 4; ++r) { pf0[mt][r] = 0.f; pf1[mt][r] = 0.f; }

    auto fstep = [&](const char* Bcur, char* Bnext, const int nt, const int ntNext) {
        if (ntNext < NT)
            for (int c = w; c < 8; c += 8)
                GLDS16(ws + OFF_F + ntNext*FCHUNK + c*1024 + lane*16, Bnext + c*1024);
        const f16* BH = (const f16*)Bcur;
        f32x4 acc[2];
        #pragma unroll
        for (int mt = 0; mt < 2; ++mt) { f32x4 z = {0.f,0.f,0.f,0.f}; acc[mt] = z; }
        #pragma unroll
        for (int kt = 0; kt < KT; ++kt) {
            const f16x8 bfr = *(const f16x8*)&BH[jl*BLDK + kt*32 + klo*8];
            acc[0] = mfma16(aF[0][kt], bfr, acc[0]);
            acc[1] = mfma16(aF[1][kt], bfr, acc[1]);
        }
        const int j = nt*16 + jl;
        const float bj = (j < HID) ? bf1[j] : 0.f;
        const float wa = (j < HID) ? Wf2[j] : 0.f;
        const float wb = (j < HID) ? Wf2[HID + j] : 0.f;
        #pragma unroll
        for (int mt = 0; mt < 2; ++mt)
            #pragma unroll
            for (int r = 0; r < 4; ++r) {
                const float h = __sinf(acc[mt][r] + bj);
                pf0[mt][r] = fmaf(wa, h, pf0[mt][r]);
                pf1[mt][r] = fmaf(wb, h, pf1[mt][r]);
            }
        __syncthreads();
    };

    #pragma unroll
    for (int ntp = 0; ntp < 6; ++ntp) {
        fstep(Bb0, Bb1, ntp*2,     ntp*2 + 1);
        fstep(Bb1, Bb0, ntp*2 + 1, ntp*2 + 2);
    }
    fstep(Bb0, Bb1, 12, NT);

    #pragma unroll
    for (int d = 1; d < 16; d <<= 1)
        #pragma unroll
        for (int mt = 0; mt < 2; ++mt)
            #pragma unroll
            for (int r = 0; r < 4; ++r) {
                pf0[mt][r] += __shfl_xor(pf0[mt][r], d);
                pf1[mt][r] += __shfl_xor(pf1[mt][r], d);
            }
    if (jl == 0) {
        #pragma unroll
        for (int mt = 0; mt < 2; ++mt) {
            const int p0 = o + mt*16 + klo*4;
            f32x4 v0, v1;
            #pragma unroll
            for (int r = 0; r < 4; ++r) {
                v0[r] = pf0[mt][r] + bf2[0];
                v1[r] = pf1[mt][r] + bf2[1];
            }
            *(f32x4*)&res[12*264 + p0] = v0;
            *(f32x4*)&res[13*264 + p0] = v1;
        }
    }
    __syncthreads();

    // ---- coalesced final store ----
    for (int e = t; e < 14*256; e += NTHREADS) {
        const int c = e >> 8, p = e & 255;
        out[(size_t)c*Np + gp0 + p] = res[c*264 + p];
    }
}

extern "C" void kernel_launch(void* const* d_in, const int* in_sizes, int n_in,
                              void* d_out, int out_size, void* d_ws, size_t ws_size,
                              hipStream_t stream) {
    const float* inp = (const float*)d_in[0];
    const float* Wu0 = (const float*)d_in[1];  const float* bu0 = (const float*)d_in[2];
    const float* Wu1 = (const float*)d_in[3];  const float* bu1 = (const float*)d_in[4];
    const float* Wu2 = (const float*)d_in[5];  const float* bu2 = (const float*)d_in[6];
    const float* Wv0 = (const float*)d_in[7];  const float* bv0 = (const float*)d_in[8];
    const float* Wv1 = (const float*)d_in[9];  const float* bv1 = (const float*)d_in[10];
    const float* Wv2 = (const float*)d_in[11]; const float* bv2 = (const float*)d_in[12];
    const float* Wf0 = (const float*)d_in[13]; const float* bf0 = (const float*)d_in[14];
    const float* Wf1 = (const float*)d_in[15]; const float* bf1 = (const float*)d_in[16];
    const float* Wf2 = (const float*)d_in[17]; const float* bf2 = (const float*)d_in[18];
    float* out = (float*)d_out;
    char* ws = (char*)d_ws;   // ~1.30 MB

    const int Np = in_sizes[0] / 3;  // 262144

    const int nTot = 2*NT*96*116 + NT*16*116 + 400 + HID;  // 314264
    dhpm_prep<<<(nTot + 255) / 256, 256, 0, stream>>>(
        Wu0, bu0, Wu1, Wv0, bv0, Wv1, Wf0, bf0, Wf1, ws);
    dhpm_main<<<Np / NPTS, NTHREADS, 0, stream>>>(
        inp, ws, bu1, Wu2, bu2, bv1, Wv2, bv2, bf1, Wf2, bf2, out, Np);
}

// Round 5
// 968.502 us; speedup vs baseline: 1.0498x; 1.0498x over previous
//
#include <hip/hip_runtime.h>

// DHPM fused forward v5 (MI355X / gfx950).
// = v4 structure (per-wave 32 points, all 6 channels in-lane, ping-pong
// global_load_lds B-staging, butterfly j-reduction, coalesced store) with
// the spill fixed: launch_bounds(512,1) allows 256 VGPR (1 block/CU), and
// the kt loop is split into sin-pass / cos-pass to keep peak pressure ~220.

#define HID 200
#define NPTS 256
#define NTHREADS 512
#define NT 13
#define KT 7
#define BLDK 232          // f16 row stride (464 B = 29 granules, odd -> quad-spread)
#define BCHUNK 45056
#define FCHUNK 8192

#define OFF_U  0
#define OFF_V  585728     // 13*45056
#define OFF_F  1171456    // 2*13*45056
#define OFF_CU 1277952
#define OFF_CV 1281152
#define OFF_CF 1284352

typedef _Float16 f16;
typedef _Float16 f16x2 __attribute__((ext_vector_type(2)));
typedef _Float16 f16x8 __attribute__((ext_vector_type(8)));
typedef float f32x4 __attribute__((ext_vector_type(4)));

#define GLDS16(gp, lp) __builtin_amdgcn_global_load_lds( \
    (const __attribute__((address_space(1))) void*)(gp), \
    (__attribute__((address_space(3))) void*)(lp), 16, 0, 0)

__global__ __launch_bounds__(256) void dhpm_prep(
    const float* __restrict__ Wu0, const float* __restrict__ bu0, const float* __restrict__ Wu1,
    const float* __restrict__ Wv0, const float* __restrict__ bv0, const float* __restrict__ Wv1,
    const float* __restrict__ Wf0, const float* __restrict__ bf0, const float* __restrict__ Wf1,
    char* __restrict__ ws)
{
    const int id = blockIdx.x * blockDim.x + threadIdx.x;
    const int nB = 2 * NT * 96 * 116;   // 289536
    const int nF = NT * 16 * 116;       // 24128
    if (id < nB) {
        int e = id;
        const int net = e / (NT*96*116); e -= net * (NT*96*116);
        const int nt  = e / (96*116);    e -= nt * (96*116);
        const int row = e / 116;
        const int k2  = e - row*116;
        const int ch  = row >> 4;
        const int j   = nt*16 + (row & 15);
        const int k   = k2*2;
        const float* W0 = net ? Wv0 : Wu0;
        const float* W1 = net ? Wv1 : Wu1;
        f16x2 v; v[0] = (f16)0.f; v[1] = (f16)0.f;
        if (j < HID) {
            #pragma unroll
            for (int s = 0; s < 2; ++s) {
                const int ks = k + s;
                if (ks < HID) {
                    const float w1 = W1[j*HID + ks];
                    const float ax = W0[ks*3+0], ay = W0[ks*3+1], at = W0[ks*3+2];
                    float gg;
                    if      (ch == 0) gg = 1.f;
                    else if (ch == 1) gg = -ax*ax;
                    else if (ch == 2) gg = -ay*ay;
                    else if (ch == 3) gg = ax;
                    else if (ch == 4) gg = ay;
                    else              gg = at;
                    v[s] = (f16)(w1 * gg);
                }
            }
        }
        *(f16x2*)(ws + (net ? OFF_V : OFF_U) + nt*BCHUNK + row*464 + k2*4) = v;
        return;
    }
    if (id < nB + nF) {
        int e = id - nB;
        const int nt  = e / (16*116);  e -= nt * (16*116);
        const int row = e / 116;
        const int k2  = e - row*116;
        const int j   = nt*16 + row;
        const int k   = k2*2;
        f16x2 v; v[0] = (f16)0.f; v[1] = (f16)0.f;
        if (j < HID) {
            if (k     < HID) v[0] = (f16)Wf1[j*HID + k];
            if (k + 1 < HID) v[1] = (f16)Wf1[j*HID + k + 1];
        }
        *(f16x2*)(ws + OFF_F + nt*FCHUNK + row*464 + k2*4) = v;
        return;
    }
    if (id < nB + nF + 400) {
        const int e = id - nB - nF;
        const int net = e / HID;
        const int r   = e - net*HID;
        const float* W0 = net ? Wv0 : Wu0;
        const float* b0 = net ? bv0 : bu0;
        float4 c;
        c.x = W0[r*3+0]; c.y = W0[r*3+1]; c.z = W0[r*3+2]; c.w = b0[r];
        *(float4*)(ws + (net ? OFF_CV : OFF_CU) + r*16) = c;
        return;
    }
    if (id < nB + nF + 400 + HID) {
        const int i = id - nB - nF - 400;
        float4 c0, c1, c2, c3;
        c0.x = Wf0[i*12+0];  c0.y = Wf0[i*12+1];  c0.z = Wf0[i*12+2];  c0.w = Wf0[i*12+3];
        c1.x = Wf0[i*12+4];  c1.y = Wf0[i*12+5];  c1.z = Wf0[i*12+6];  c1.w = Wf0[i*12+7];
        c2.x = Wf0[i*12+8];  c2.y = Wf0[i*12+9];  c2.z = Wf0[i*12+10]; c2.w = Wf0[i*12+11];
        c3.x = bf0[i]; c3.y = 0.f; c3.z = 0.f; c3.w = 0.f;
        char* p = ws + OFF_CF + i*64;
        *(float4*)(p)      = c0;
        *(float4*)(p + 16) = c1;
        *(float4*)(p + 32) = c2;
        *(float4*)(p + 48) = c3;
    }
}

__device__ __forceinline__ f32x4 mfma16(f16x8 a, f16x8 b, f32x4 c) {
    return __builtin_amdgcn_mfma_f32_16x16x32_f16(a, b, c, 0, 0, 0);
}

__device__ __forceinline__ void run_net(
    const float* __restrict__ inp, const char* __restrict__ ws,
    const int cstOff, const int bOff,
    const float* __restrict__ b1, const float* __restrict__ W2, const float b2s,
    const int cV, const int cXX, const int cYY,
    const int cX, const int cY, const int cT,
    char* __restrict__ Bb0, char* __restrict__ Bb1, float* __restrict__ res,
    const int gp0)
{
    const int t = threadIdx.x;
    const int lane = t & 63;
    const int w = __builtin_amdgcn_readfirstlane(t >> 6);
    const int jl = lane & 15, klo = lane >> 4;
    const int o = w * 32;
    const char* bsrc = ws + bOff;

    // stage nt=0 -> Bb0 (overlaps A-build)
    for (int c = w; c < 44; c += 8)
        GLDS16(bsrc + c*1024 + lane*16, Bb0 + c*1024);

    // ---- sin & cos A-fragments, register resident (112 VGPR) ----
    f16x8 aS[2][KT], aC[2][KT];
    {
        const float4* cst = (const float4*)(ws + cstOff);
        #pragma unroll
        for (int mt = 0; mt < 2; ++mt) {
            const int prow = gp0 + o + mt*16 + jl;
            const float x = inp[prow*3+0], y = inp[prow*3+1], tt = inp[prow*3+2];
            #pragma unroll
            for (int kt = 0; kt < KT; ++kt) {
                f16x8 fs, fc;
                #pragma unroll
                for (int e = 0; e < 8; ++e) {
                    const int i = kt*32 + klo*8 + e;
                    const float4 c = cst[(i < HID) ? i : 0];   // pad k hits zero B'
                    const float z = fmaf(c.x, x, fmaf(c.y, y, fmaf(c.z, tt, c.w)));
                    float sv, cv;
                    __sincosf(z, &sv, &cv);
                    fs[e] = (f16)sv; fc[e] = (f16)cv;
                }
                aS[mt][kt] = fs; aC[mt][kt] = fc;
            }
        }
    }

    float pV[2][4], pXX[2][4], pYY[2][4], pX[2][4], pY[2][4], pT[2][4];
    #pragma unroll
    for (int mt = 0; mt < 2; ++mt)
        #pragma unroll
        for (int r = 0; r < 4; ++r) {
            pV[mt][r]=0.f; pXX[mt][r]=0.f; pYY[mt][r]=0.f;
            pX[mt][r]=0.f; pY[mt][r]=0.f; pT[mt][r]=0.f;
        }

    __syncthreads();   // Bb0 landed (implicit vmcnt drain before barrier)

    auto step = [&](const char* Bcur, char* Bnext, const int nt, const int ntNext) {
        if (ntNext < NT)   // prefetch next tile into the other buffer
            for (int c = w; c < 44; c += 8)
                GLDS16(bsrc + ntNext*BCHUNK + c*1024 + lane*16, Bnext + c*1024);

        const f16* BH = (const f16*)Bcur;
        f32x4 accS[3][2], accC[3][2];
        #pragma unroll
        for (int c = 0; c < 3; ++c)
            #pragma unroll
            for (int mt = 0; mt < 2; ++mt) {
                f32x4 z = {0.f,0.f,0.f,0.f};
                accS[c][mt] = z; accC[c][mt] = z;
            }
        // ---- pass 1: sin channels (val, xx, yy) ----
        #pragma unroll
        for (int kt = 0; kt < KT; ++kt) {
            f16x8 bfr[3];
            #pragma unroll
            for (int c = 0; c < 3; ++c)
                bfr[c] = *(const f16x8*)&BH[(c*16 + jl)*BLDK + kt*32 + klo*8];
            #pragma unroll
            for (int c = 0; c < 3; ++c) {
                accS[c][0] = mfma16(aS[0][kt], bfr[c], accS[c][0]);
                accS[c][1] = mfma16(aS[1][kt], bfr[c], accS[c][1]);
            }
        }
        // ---- pass 2: cos channels (dx, dy, dt) ----
        #pragma unroll
        for (int kt = 0; kt < KT; ++kt) {
            f16x8 bfr[3];
            #pragma unroll
            for (int c = 0; c < 3; ++c)
                bfr[c] = *(const f16x8*)&BH[((c+3)*16 + jl)*BLDK + kt*32 + klo*8];
            #pragma unroll
            for (int c = 0; c < 3; ++c) {
                accC[c][0] = mfma16(aC[0][kt], bfr[c], accC[c][0]);
                accC[c][1] = mfma16(aC[1][kt], bfr[c], accC[c][1]);
            }
        }

        // ---- in-lane epilogue: lane owns (j=jl, pts klo*4+r) with all 6 Y ----
        const int j = nt*16 + jl;
        const float b1j = (j < HID) ? b1[j] : 0.f;
        const float w2j = (j < HID) ? W2[j] : 0.f;   // 0 kills pad-j
        #pragma unroll
        for (int mt = 0; mt < 2; ++mt)
            #pragma unroll
            for (int r = 0; r < 4; ++r) {
                float s1, c1;
                __sincosf(accS[0][mt][r] + b1j, &s1, &c1);
                const float wc = w2j*c1, wsn = w2j*s1;
                const float ydx = accC[0][mt][r], ydy = accC[1][mt][r];
                pV[mt][r]  += wsn;
                pXX[mt][r] = fmaf(wc, accS[1][mt][r], fmaf(-wsn*ydx, ydx, pXX[mt][r]));
                pYY[mt][r] = fmaf(wc, accS[2][mt][r], fmaf(-wsn*ydy, ydy, pYY[mt][r]));
                pX[mt][r]  = fmaf(wc, ydx, pX[mt][r]);
                pY[mt][r]  = fmaf(wc, ydy, pY[mt][r]);
                pT[mt][r]  = fmaf(wc, accC[2][mt][r], pT[mt][r]);
            }
        __syncthreads();   // all reads of Bcur done; Bnext landed
    };

    #pragma unroll
    for (int ntp = 0; ntp < 6; ++ntp) {
        step(Bb0, Bb1, ntp*2,     ntp*2 + 1);
        step(Bb1, Bb0, ntp*2 + 1, ntp*2 + 2);
    }
    step(Bb0, Bb1, 12, NT);   // last tile, no prefetch

    // ---- butterfly over the 16 j-lanes ----
    #pragma unroll
    for (int d = 1; d < 16; d <<= 1)
        #pragma unroll
        for (int mt = 0; mt < 2; ++mt)
            #pragma unroll
            for (int r = 0; r < 4; ++r) {
                pV[mt][r]  += __shfl_xor(pV[mt][r],  d);
                pXX[mt][r] += __shfl_xor(pXX[mt][r], d);
                pYY[mt][r] += __shfl_xor(pYY[mt][r], d);
                pX[mt][r]  += __shfl_xor(pX[mt][r],  d);
                pY[mt][r]  += __shfl_xor(pY[mt][r],  d);
                pT[mt][r]  += __shfl_xor(pT[mt][r],  d);
            }
    if (jl == 0) {
        #pragma unroll
        for (int mt = 0; mt < 2; ++mt) {
            const int p0 = o + mt*16 + klo*4;
            f32x4 vv;
            #pragma unroll
            for (int r = 0; r < 4; ++r) vv[r] = pV[mt][r] + b2s;
            *(f32x4*)&res[cV*264 + p0] = vv;
            #pragma unroll
            for (int r = 0; r < 4; ++r) vv[r] = pXX[mt][r];
            *(f32x4*)&res[cXX*264 + p0] = vv;
            #pragma unroll
            for (int r = 0; r < 4; ++r) vv[r] = pYY[mt][r];
            *(f32x4*)&res[cYY*264 + p0] = vv;
            #pragma unroll
            for (int r = 0; r < 4; ++r) vv[r] = pX[mt][r];
            *(f32x4*)&res[cX*264 + p0] = vv;
            #pragma unroll
            for (int r = 0; r < 4; ++r) vv[r] = pY[mt][r];
            *(f32x4*)&res[cY*264 + p0] = vv;
            #pragma unroll
            for (int r = 0; r < 4; ++r) vv[r] = pT[mt][r];
            *(f32x4*)&res[cT*264 + p0] = vv;
        }
    }
}

__global__ __launch_bounds__(NTHREADS, 1) void dhpm_main(
    const float* __restrict__ inp, const char* __restrict__ ws,
    const float* __restrict__ bu1, const float* __restrict__ Wu2, const float* __restrict__ bu2,
    const float* __restrict__ bv1, const float* __restrict__ Wv2, const float* __restrict__ bv2,
    const float* __restrict__ bf1, const float* __restrict__ Wf2, const float* __restrict__ bf2,
    float* __restrict__ out, const int Np)
{
    __shared__ __align__(16) char Bb0[BCHUNK];
    __shared__ __align__(16) char Bb1[BCHUNK];
    __shared__ __align__(16) float res[14*264];   // 14784 B

    const int t = threadIdx.x;
    const int lane = t & 63;
    const int w = __builtin_amdgcn_readfirstlane(t >> 6);
    const int jl = lane & 15, klo = lane >> 4;
    const int o = w * 32;
    const int gp0 = blockIdx.x * NPTS;

    run_net(inp, ws, OFF_CU, OFF_U, bu1, Wu2, bu2[0], 0, 5, 7, 4, 6, 2,
            Bb0, Bb1, res, gp0);
    run_net(inp, ws, OFF_CV, OFF_V, bv1, Wv2, bv2[0], 1, 9, 11, 8, 10, 3,
            Bb0, Bb1, res, gp0);

    // ======================= f-net =======================
    for (int c = w; c < 8; c += 8)
        GLDS16(ws + OFF_F + c*1024 + lane*16, Bb0 + c*1024);
    __syncthreads();   // res cols 0..11 complete + f tile 0 landed

    f16x8 aF[2][KT];
    {
        const float4* cf = (const float4*)(ws + OFF_CF);
        #pragma unroll
        for (int mt = 0; mt < 2; ++mt) {
            const int p = o + mt*16 + jl;
            float fv[12];
            #pragma unroll
            for (int k = 0; k < 12; ++k) fv[k] = res[k*264 + p];
            #pragma unroll
            for (int kt = 0; kt < KT; ++kt) {
                f16x8 f;
                #pragma unroll
                for (int e = 0; e < 8; ++e) {
                    const int i = kt*32 + klo*8 + e;
                    const int ic = (i < HID) ? i : 0;
                    const float4 c0 = cf[ic*4+0];
                    const float4 c1 = cf[ic*4+1];
                    const float4 c2 = cf[ic*4+2];
                    const float4 c3 = cf[ic*4+3];
                    float z = c3.x;
                    z = fmaf(c0.x, fv[0], z);  z = fmaf(c0.y, fv[1], z);
                    z = fmaf(c0.z, fv[2], z);  z = fmaf(c0.w, fv[3], z);
                    z = fmaf(c1.x, fv[4], z);  z = fmaf(c1.y, fv[5], z);
                    z = fmaf(c1.z, fv[6], z);  z = fmaf(c1.w, fv[7], z);
                    z = fmaf(c2.x, fv[8], z);  z = fmaf(c2.y, fv[9], z);
                    z = fmaf(c2.z, fv[10], z); z = fmaf(c2.w, fv[11], z);
                    f[e] = (f16)__sinf(z);
                }
                aF[mt][kt] = f;
            }
        }
    }

    float pf0[2][4], pf1[2][4];
    #pragma unroll
    for (int mt = 0; mt < 2; ++mt)
        #pragma unroll
        for (int r = 0; r < 4; ++r) { pf0[mt][r] = 0.f; pf1[mt][r] = 0.f; }

    auto fstep = [&](const char* Bcur, char* Bnext, const int nt, const int ntNext) {
        if (ntNext < NT)
            for (int c = w; c < 8; c += 8)
                GLDS16(ws + OFF_F + ntNext*FCHUNK + c*1024 + lane*16, Bnext + c*1024);
        const f16* BH = (const f16*)Bcur;
        f32x4 acc[2];
        #pragma unroll
        for (int mt = 0; mt < 2; ++mt) { f32x4 z = {0.f,0.f,0.f,0.f}; acc[mt] = z; }
        #pragma unroll
        for (int kt = 0; kt < KT; ++kt) {
            const f16x8 bfr = *(const f16x8*)&BH[jl*BLDK + kt*32 + klo*8];
            acc[0] = mfma16(aF[0][kt], bfr, acc[0]);
            acc[1] = mfma16(aF[1][kt], bfr, acc[1]);
        }
        const int j = nt*16 + jl;
        const float bj = (j < HID) ? bf1[j] : 0.f;
        const float wa = (j < HID) ? Wf2[j] : 0.f;
        const float wb = (j < HID) ? Wf2[HID + j] : 0.f;
        #pragma unroll
        for (int mt = 0; mt < 2; ++mt)
            #pragma unroll
            for (int r = 0; r < 4; ++r) {
                const float h = __sinf(acc[mt][r] + bj);
                pf0[mt][r] = fmaf(wa, h, pf0[mt][r]);
                pf1[mt][r] = fmaf(wb, h, pf1[mt][r]);
            }
        __syncthreads();
    };

    #pragma unroll
    for (int ntp = 0; ntp < 6; ++ntp) {
        fstep(Bb0, Bb1, ntp*2,     ntp*2 + 1);
        fstep(Bb1, Bb0, ntp*2 + 1, ntp*2 + 2);
    }
    fstep(Bb0, Bb1, 12, NT);

    #pragma unroll
    for (int d = 1; d < 16; d <<= 1)
        #pragma unroll
        for (int mt = 0; mt < 2; ++mt)
            #pragma unroll
            for (int r = 0; r < 4; ++r) {
                pf0[mt][r] += __shfl_xor(pf0[mt][r], d);
                pf1[mt][r] += __shfl_xor(pf1[mt][r], d);
            }
    if (jl == 0) {
        #pragma unroll
        for (int mt = 0; mt < 2; ++mt) {
            const int p0 = o + mt*16 + klo*4;
            f32x4 v0, v1;
            #pragma unroll
            for (int r = 0; r < 4; ++r) {
                v0[r] = pf0[mt][r] + bf2[0];
                v1[r] = pf1[mt][r] + bf2[1];
            }
            *(f32x4*)&res[12*264 + p0] = v0;
            *(f32x4*)&res[13*264 + p0] = v1;
        }
    }
    __syncthreads();

    // ---- coalesced final store ----
    for (int e = t; e < 14*256; e += NTHREADS) {
        const int c = e >> 8, p = e & 255;
        out[(size_t)c*Np + gp0 + p] = res[c*264 + p];
    }
}

extern "C" void kernel_launch(void* const* d_in, const int* in_sizes, int n_in,
                              void* d_out, int out_size, void* d_ws, size_t ws_size,
                              hipStream_t stream) {
    const float* inp = (const float*)d_in[0];
    const float* Wu0 = (const float*)d_in[1];  const float* bu0 = (const float*)d_in[2];
    const float* Wu1 = (const float*)d_in[3];  const float* bu1 = (const float*)d_in[4];
    const float* Wu2 = (const float*)d_in[5];  const float* bu2 = (const float*)d_in[6];
    const float* Wv0 = (const float*)d_in[7];  const float* bv0 = (const float*)d_in[8];
    const float* Wv1 = (const float*)d_in[9];  const float* bv1 = (const float*)d_in[10];
    const float* Wv2 = (const float*)d_in[11]; const float* bv2 = (const float*)d_in[12];
    const float* Wf0 = (const float*)d_in[13]; const float* bf0 = (const float*)d_in[14];
    const float* Wf1 = (const float*)d_in[15]; const float* bf1 = (const float*)d_in[16];
    const float* Wf2 = (const float*)d_in[17]; const float* bf2 = (const float*)d_in[18];
    float* out = (float*)d_out;
    char* ws = (char*)d_ws;   // ~1.30 MB

    const int Np = in_sizes[0] / 3;  // 262144

    const int nTot = 2*NT*96*116 + NT*16*116 + 400 + HID;  // 314264
    dhpm_prep<<<(nTot + 255) / 256, 256, 0, stream>>>(
        Wu0, bu0, Wu1, Wv0, bv0, Wv1, Wf0, bf0, Wf1, ws);
    dhpm_main<<<Np / NPTS, NTHREADS, 0, stream>>>(
        inp, ws, bu1, Wu2, bu2, bv1, Wv2, bv2, bf1, Wf2, bf2, out, Np);
}

// Round 6
// 757.930 us; speedup vs baseline: 1.3415x; 1.2778x over previous
//
#include <hip/hip_runtime.h>

// DHPM fused forward v6 (MI355X / gfx950).
// Key change vs v5: fold the per-k diagonal scalings g_c into the A side
// (A'_c[pt,k] = trig(z0[pt,k]) * g_c[k], in registers), keep B = raw W1 f16
// tile in LDS. Per K-step: ONE ds_read_b128 -> SIX MFMAs (was 6 reads -> 12).
// 256-thr blocks (4 waves, 16 pts/wave) keep register demand ~240 <= 256.
// f-net: j-split across waves, Wf1 fragments register-resident (from L2),
// shared A_f tile in LDS, cross-wave reduction for the final 2 outputs.

#define HID 200
#define NT 13
#define KT 7
#define BLDK 232           // f16 row stride of W tiles (464 B)
#define WCHUNK 8192        // padded per-nt tile chunk in ws
#define NTH 256

#define OFF_WU 0           // [13][16][232] f16 (8 KB padded per nt)
#define OFF_WV 106496
#define OFF_WF 212992
#define OFF_CU 319488      // [200] float4 {ax,ay,at,b0}
#define OFF_CV 322688
#define OFF_CF 325888      // [200][16] f32 {Wf0 row(12), bf0, pad}

typedef _Float16 f16;
typedef _Float16 f16x2 __attribute__((ext_vector_type(2)));
typedef _Float16 f16x8 __attribute__((ext_vector_type(8)));
typedef float f32x4 __attribute__((ext_vector_type(4)));

#define GLDS16(gp, lp) __builtin_amdgcn_global_load_lds( \
    (const __attribute__((address_space(1))) void*)(gp), \
    (__attribute__((address_space(3))) void*)(lp), 16, 0, 0)

__global__ __launch_bounds__(256) void dhpm_prep(
    const float* __restrict__ Wu1, const float* __restrict__ Wv1, const float* __restrict__ Wf1,
    const float* __restrict__ Wu0, const float* __restrict__ bu0,
    const float* __restrict__ Wv0, const float* __restrict__ bv0,
    const float* __restrict__ Wf0, const float* __restrict__ bf0,
    char* __restrict__ ws)
{
    int id = blockIdx.x * blockDim.x + threadIdx.x;
    const int nW = 3 * NT * 16 * 116;   // 72384
    if (id < nW) {
        const int net = id / (NT*16*116);
        int e = id - net * (NT*16*116);
        const int nt  = e / (16*116);  e -= nt * (16*116);
        const int row = e / 116;
        const int k2  = e - row * 116;
        const int j   = nt*16 + row;
        const int k   = k2*2;
        const float* W = (net == 0) ? Wu1 : (net == 1) ? Wv1 : Wf1;
        f16x2 v; v[0] = (f16)0.f; v[1] = (f16)0.f;
        if (j < HID) {
            if (k     < HID) v[0] = (f16)W[j*HID + k];
            if (k + 1 < HID) v[1] = (f16)W[j*HID + k + 1];
        }
        *(f16x2*)(ws + net*106496 + nt*WCHUNK + row*464 + k2*4) = v;
        return;
    }
    id -= nW;
    if (id < 400) {
        const int net = id / HID;
        const int r   = id - net*HID;
        const float* W0 = net ? Wv0 : Wu0;
        const float* b0 = net ? bv0 : bu0;
        float4 c;
        c.x = W0[r*3+0]; c.y = W0[r*3+1]; c.z = W0[r*3+2]; c.w = b0[r];
        *(float4*)(ws + (net ? OFF_CV : OFF_CU) + r*16) = c;
        return;
    }
    id -= 400;
    if (id < HID) {
        const int i = id;
        float4 c0, c1, c2, c3;
        c0.x = Wf0[i*12+0];  c0.y = Wf0[i*12+1];  c0.z = Wf0[i*12+2];  c0.w = Wf0[i*12+3];
        c1.x = Wf0[i*12+4];  c1.y = Wf0[i*12+5];  c1.z = Wf0[i*12+6];  c1.w = Wf0[i*12+7];
        c2.x = Wf0[i*12+8];  c2.y = Wf0[i*12+9];  c2.z = Wf0[i*12+10]; c2.w = Wf0[i*12+11];
        c3.x = bf0[i]; c3.y = 0.f; c3.z = 0.f; c3.w = 0.f;
        char* p = ws + OFF_CF + i*64;
        *(float4*)(p)      = c0;
        *(float4*)(p + 16) = c1;
        *(float4*)(p + 32) = c2;
        *(float4*)(p + 48) = c3;
    }
}

__device__ __forceinline__ f32x4 mfma16(f16x8 a, f16x8 b, f32x4 c) {
    return __builtin_amdgcn_mfma_f32_16x16x32_f16(a, b, c, 0, 0, 0);
}

__device__ __forceinline__ void run_net(
    const float* __restrict__ inp, const char* __restrict__ ws,
    const int wOff, const int cstOff,
    const float* __restrict__ b1, const float* __restrict__ W2, const float b2s,
    const int cV, const int cXX, const int cYY,
    const int cX, const int cY, const int cT,
    char* __restrict__ Bb0, char* __restrict__ Bb1, float* __restrict__ res,
    const int gp0, const int o, const int lane, const int w,
    const int jl, const int klo)
{
    const char* src = ws + wOff;

    // stage nt=0 -> Bb0 (overlaps A'-build)
    for (int c = w; c < 8; c += 4)
        GLDS16(src + c*1024 + lane*16, Bb0 + c*1024);

    // ---- A'-fragments: 6 channels x 7 kt, register resident (168 VGPR) ----
    f16x8 aP[6][KT];
    {
        const float4* cst = (const float4*)(ws + cstOff);
        const int pt = gp0 + o + jl;
        const float x = inp[pt*3+0], y = inp[pt*3+1], tt = inp[pt*3+2];
        #pragma unroll
        for (int kt = 0; kt < KT; ++kt) {
            f16x8 f0, f1, f2, f3, f4, f5;
            #pragma unroll
            for (int e = 0; e < 8; ++e) {
                const int i = kt*32 + klo*8 + e;
                const float4 c = cst[(i < HID) ? i : 0];  // pad-k hits zero B
                const float z = fmaf(c.x, x, fmaf(c.y, y, fmaf(c.z, tt, c.w)));
                float s, cv;
                __sincosf(z, &s, &cv);
                f0[e] = (f16)s;
                f1[e] = (f16)(-s * c.x * c.x);
                f2[e] = (f16)(-s * c.y * c.y);
                f3[e] = (f16)(cv * c.x);
                f4[e] = (f16)(cv * c.y);
                f5[e] = (f16)(cv * c.z);
            }
            aP[0][kt] = f0; aP[1][kt] = f1; aP[2][kt] = f2;
            aP[3][kt] = f3; aP[4][kt] = f4; aP[5][kt] = f5;
        }
    }

    float pV[4]  = {0,0,0,0}, pXX[4] = {0,0,0,0}, pYY[4] = {0,0,0,0};
    float pX[4]  = {0,0,0,0}, pY[4]  = {0,0,0,0}, pT[4]  = {0,0,0,0};

    __syncthreads();   // Bb0 landed; prior-phase LDS reads done

    auto step = [&](const char* Bcur, char* Bnext, const int nt, const int ntNext) {
        if (ntNext < NT)
            for (int c = w; c < 8; c += 4)
                GLDS16(src + ntNext*WCHUNK + c*1024 + lane*16, Bnext + c*1024);

        const f16* BH = (const f16*)Bcur;
        f32x4 acc[6];
        #pragma unroll
        for (int c6 = 0; c6 < 6; ++c6) { f32x4 z = {0.f,0.f,0.f,0.f}; acc[c6] = z; }
        #pragma unroll
        for (int kt = 0; kt < KT; ++kt) {
            const f16x8 b = *(const f16x8*)&BH[jl*BLDK + kt*32 + klo*8];
            #pragma unroll
            for (int c6 = 0; c6 < 6; ++c6)
                acc[c6] = mfma16(aP[c6][kt], b, acc[c6]);
        }

        // in-lane epilogue: lane owns (j = nt*16+jl, pts klo*4+r), all 6 Y
        const int j = nt*16 + jl;
        const float b1j = (j < HID) ? b1[j] : 0.f;
        const float w2j = (j < HID) ? W2[j] : 0.f;
        #pragma unroll
        for (int r = 0; r < 4; ++r) {
            float s1, c1;
            __sincosf(acc[0][r] + b1j, &s1, &c1);
            const float wc = w2j*c1, wsn = w2j*s1;
            const float ydx = acc[3][r], ydy = acc[4][r];
            pV[r]  += wsn;
            pXX[r] = fmaf(wc, acc[1][r], fmaf(-wsn*ydx, ydx, pXX[r]));
            pYY[r] = fmaf(wc, acc[2][r], fmaf(-wsn*ydy, ydy, pYY[r]));
            pX[r]  = fmaf(wc, ydx, pX[r]);
            pY[r]  = fmaf(wc, ydy, pY[r]);
            pT[r]  = fmaf(wc, acc[5][r], pT[r]);
        }
        __syncthreads();   // Bcur reads done; Bnext landed
    };

    #pragma unroll
    for (int p2 = 0; p2 < 6; ++p2) {
        step(Bb0, Bb1, 2*p2,     2*p2 + 1);
        step(Bb1, Bb0, 2*p2 + 1, 2*p2 + 2);
    }
    step(Bb0, Bb1, 12, NT);

    // butterfly over the 16 j-lanes
    #pragma unroll
    for (int d = 1; d < 16; d <<= 1)
        #pragma unroll
        for (int r = 0; r < 4; ++r) {
            pV[r]  += __shfl_xor(pV[r],  d);
            pXX[r] += __shfl_xor(pXX[r], d);
            pYY[r] += __shfl_xor(pYY[r], d);
            pX[r]  += __shfl_xor(pX[r],  d);
            pY[r]  += __shfl_xor(pY[r],  d);
            pT[r]  += __shfl_xor(pT[r],  d);
        }
    if (jl == 0) {
        const int p0 = o + klo*4;
        f32x4 v;
        #pragma unroll
        for (int r = 0; r < 4; ++r) v[r] = pV[r] + b2s;
        *(f32x4*)&res[cV*72 + p0] = v;
        #pragma unroll
        for (int r = 0; r < 4; ++r) v[r] = pXX[r];
        *(f32x4*)&res[cXX*72 + p0] = v;
        #pragma unroll
        for (int r = 0; r < 4; ++r) v[r] = pYY[r];
        *(f32x4*)&res[cYY*72 + p0] = v;
        #pragma unroll
        for (int r = 0; r < 4; ++r) v[r] = pX[r];
        *(f32x4*)&res[cX*72 + p0] = v;
        #pragma unroll
        for (int r = 0; r < 4; ++r) v[r] = pY[r];
        *(f32x4*)&res[cY*72 + p0] = v;
        #pragma unroll
        for (int r = 0; r < 4; ++r) v[r] = pT[r];
        *(f32x4*)&res[cT*72 + p0] = v;
    }
}

__global__ __launch_bounds__(NTH, 2) void dhpm_main(
    const float* __restrict__ inp, const char* __restrict__ ws,
    const float* __restrict__ bu1, const float* __restrict__ Wu2, const float* __restrict__ bu2,
    const float* __restrict__ bv1, const float* __restrict__ Wv2, const float* __restrict__ bv2,
    const float* __restrict__ bf1, const float* __restrict__ Wf2, const float* __restrict__ bf2,
    float* __restrict__ out, const int Np)
{
    __shared__ __align__(16) char LDS[35776];
    char*  Bb0 = LDS;                       // 8 KB   (main nets)
    char*  Bb1 = LDS + WCHUNK;              // 8 KB   (main nets)
    f16*   Af  = (f16*)LDS;                 // 29696 B [64 pts][232 k] (f-net)
    float* res = (float*)(LDS + 29696);     // [14][72] f32 = 4032 B
    float* pfb = (float*)(LDS + 33728);     // [4][2][64] f32 = 2048 B

    const int t = threadIdx.x;
    const int lane = t & 63;
    const int w = __builtin_amdgcn_readfirstlane(t >> 6);
    const int jl = lane & 15, klo = lane >> 4;
    const int o = w * 16;
    const int gp0 = blockIdx.x * 64;

    run_net(inp, ws, OFF_WU, OFF_CU, bu1, Wu2, bu2[0], 0, 5, 7, 4, 6, 2,
            Bb0, Bb1, res, gp0, o, lane, w, jl, klo);
    run_net(inp, ws, OFF_WV, OFF_CV, bv1, Wv2, bv2[0], 1, 9, 11, 8, 10, 3,
            Bb0, Bb1, res, gp0, o, lane, w, jl, klo);

    // ======================= f-net =======================
    // j-split: wave w owns nt = w, w+4, w+8 (+ nt 12 for wave 0); Wf1
    // fragments live in registers (from L2-resident ws); A_f in LDS.
    const int nown = (w == 0) ? 4 : 3;
    f16x8 bF[4][KT];
    #pragma unroll
    for (int ont = 0; ont < 4; ++ont)
        if (ont < nown) {
            const int nt = w + ont*4;
            #pragma unroll
            for (int kt = 0; kt < KT; ++kt)
                bF[ont][kt] = *(const f16x8*)(ws + OFF_WF + nt*WCHUNK
                                              + jl*464 + kt*64 + klo*16);
        }

    // A_f build: lane owns pt = o + jl (its own wave's res rows; intra-wave
    // LDS visibility needs no barrier)
    {
        float fv[12];
        #pragma unroll
        for (int k = 0; k < 12; ++k) fv[k] = res[k*72 + o + jl];
        const float4* cf = (const float4*)(ws + OFF_CF);
        #pragma unroll
        for (int kt = 0; kt < KT; ++kt) {
            f16x8 f;
            #pragma unroll
            for (int e = 0; e < 8; ++e) {
                const int i = kt*32 + klo*8 + e;
                const int ic = (i < HID) ? i : 0;
                const float4 c0 = cf[ic*4+0];
                const float4 c1 = cf[ic*4+1];
                const float4 c2 = cf[ic*4+2];
                const float4 c3 = cf[ic*4+3];
                float z = c3.x;
                z = fmaf(c0.x, fv[0], z);  z = fmaf(c0.y, fv[1], z);
                z = fmaf(c0.z, fv[2], z);  z = fmaf(c0.w, fv[3], z);
                z = fmaf(c1.x, fv[4], z);  z = fmaf(c1.y, fv[5], z);
                z = fmaf(c1.z, fv[6], z);  z = fmaf(c1.w, fv[7], z);
                z = fmaf(c2.x, fv[8], z);  z = fmaf(c2.y, fv[9], z);
                z = fmaf(c2.z, fv[10], z); z = fmaf(c2.w, fv[11], z);
                f[e] = (f16)__sinf(z);
            }
            *(f16x8*)((char*)Af + (o + jl)*464 + kt*64 + klo*16) = f;
        }
    }
    __syncthreads();   // A_f complete (Bb region safely overwritten)

    f32x4 accF[4][4];
    #pragma unroll
    for (int ont = 0; ont < 4; ++ont)
        #pragma unroll
        for (int mt = 0; mt < 4; ++mt) { f32x4 z = {0.f,0.f,0.f,0.f}; accF[ont][mt] = z; }

    #pragma unroll
    for (int kt = 0; kt < KT; ++kt)
        #pragma unroll
        for (int mt = 0; mt < 4; ++mt) {
            const f16x8 a = *(const f16x8*)((const char*)Af
                                + (mt*16 + jl)*464 + kt*64 + klo*16);
            #pragma unroll
            for (int ont = 0; ont < 4; ++ont)
                if (ont < nown)
                    accF[ont][mt] = mfma16(a, bF[ont][kt], accF[ont][mt]);
        }

    float pf0[4][4], pf1[4][4];
    #pragma unroll
    for (int mt = 0; mt < 4; ++mt)
        #pragma unroll
        for (int r = 0; r < 4; ++r) { pf0[mt][r] = 0.f; pf1[mt][r] = 0.f; }

    #pragma unroll
    for (int ont = 0; ont < 4; ++ont)
        if (ont < nown) {
            const int j = (w + ont*4)*16 + jl;
            const float bj = (j < HID) ? bf1[j] : 0.f;
            const float wa = (j < HID) ? Wf2[j] : 0.f;
            const float wb = (j < HID) ? Wf2[HID + j] : 0.f;
            #pragma unroll
            for (int mt = 0; mt < 4; ++mt)
                #pragma unroll
                for (int r = 0; r < 4; ++r) {
                    const float h = __sinf(accF[ont][mt][r] + bj);
                    pf0[mt][r] = fmaf(wa, h, pf0[mt][r]);
                    pf1[mt][r] = fmaf(wb, h, pf1[mt][r]);
                }
        }

    #pragma unroll
    for (int d = 1; d < 16; d <<= 1)
        #pragma unroll
        for (int mt = 0; mt < 4; ++mt)
            #pragma unroll
            for (int r = 0; r < 4; ++r) {
                pf0[mt][r] += __shfl_xor(pf0[mt][r], d);
                pf1[mt][r] += __shfl_xor(pf1[mt][r], d);
            }
    if (jl == 0) {
        #pragma unroll
        for (int mt = 0; mt < 4; ++mt) {
            f32x4 v0, v1;
            #pragma unroll
            for (int r = 0; r < 4; ++r) { v0[r] = pf0[mt][r]; v1[r] = pf1[mt][r]; }
            *(f32x4*)&pfb[w*128 + 0*64 + mt*16 + klo*4] = v0;
            *(f32x4*)&pfb[w*128 + 1*64 + mt*16 + klo*4] = v1;  // NOTE: fixed below
        }
    }
    __syncthreads();
    if (t < 128) {
        const int pt = t & 63, ch = t >> 6;
        float s = bf2[ch];
        #pragma unroll
        for (int ww = 0; ww < 4; ++ww) s += pfb[ww*128 + ch*64 + pt];
        res[(12 + ch)*72 + pt] = s;
    }
    __syncthreads();

    // coalesced final store
    for (int e = t; e < 14*64; e += NTH) {
        const int c = e >> 6, p = e & 63;
        out[(size_t)c*Np + gp0 + p] = res[c*72 + p];
    }
}

extern "C" void kernel_launch(void* const* d_in, const int* in_sizes, int n_in,
                              void* d_out, int out_size, void* d_ws, size_t ws_size,
                              hipStream_t stream) {
    const float* inp = (const float*)d_in[0];
    const float* Wu0 = (const float*)d_in[1];  const float* bu0 = (const float*)d_in[2];
    const float* Wu1 = (const float*)d_in[3];  const float* bu1 = (const float*)d_in[4];
    const float* Wu2 = (const float*)d_in[5];  const float* bu2 = (const float*)d_in[6];
    const float* Wv0 = (const float*)d_in[7];  const float* bv0 = (const float*)d_in[8];
    const float* Wv1 = (const float*)d_in[9];  const float* bv1 = (const float*)d_in[10];
    const float* Wv2 = (const float*)d_in[11]; const float* bv2 = (const float*)d_in[12];
    const float* Wf0 = (const float*)d_in[13]; const float* bf0 = (const float*)d_in[14];
    const float* Wf1 = (const float*)d_in[15]; const float* bf1 = (const float*)d_in[16];
    const float* Wf2 = (const float*)d_in[17]; const float* bf2 = (const float*)d_in[18];
    float* out = (float*)d_out;
    char* ws = (char*)d_ws;   // ~340 KB used

    const int Np = in_sizes[0] / 3;  // 262144

    const int nTot = 3*NT*16*116 + 400 + HID;  // 72984
    dhpm_prep<<<(nTot + NTH - 1) / NTH, NTH, 0, stream>>>(
        Wu1, Wv1, Wf1, Wu0, bu0, Wv0, bv0, Wf0, bf0, ws);
    dhpm_main<<<Np / 64, NTH, 0, stream>>>(
        inp, ws, bu1, Wu2, bu2, bv1, Wv2, bv2, bf1, Wf2, bf2, out, Np);
}

// Round 7
// 718.301 us; speedup vs baseline: 1.4155x; 1.0552x over previous
//
#include <hip/hip_runtime.h>

// DHPM fused forward v7 (MI355X / gfx950).
// vs v6: 6 channels split across wave PAIRS so arch-VGPR demand fits the
// observed 128-reg cap (no spill). 512 thr = 8 waves = 4 pt-groups x 2
// trig-groups; each wave: aP[3][7] (84 VGPR) A-side-folded fragments,
// 1 ds_read_b128 -> 3 MFMAs per K-step. Epilogue coupling via odd-stride
// LDS exchange (wc one way, Ydx/Ydy the other). f-net: j-split, <=2 tiles
// per wave (bF[2][7] = 56 VGPR).

#define HID 200
#define NT 13
#define KT 7
#define BLDK 232           // f16 row stride of W tiles (464 B = 29 granules, odd)
#define WCHUNK 8192
#define NTH 512
#define ELD 68             // exchange row stride (floats; 17 granules, odd)

#define OFF_WU 0           // [13][16][232] f16, 8 KB padded per nt
#define OFF_WV 106496
#define OFF_WF 212992
#define OFF_CU 319488      // [200] float4 {ax,ay,at,b0}
#define OFF_CV 322688
#define OFF_CF 325888      // [200][16] f32 {Wf0 row(12), bf0, pad}

typedef _Float16 f16;
typedef _Float16 f16x2 __attribute__((ext_vector_type(2)));
typedef _Float16 f16x8 __attribute__((ext_vector_type(8)));
typedef float f32x4 __attribute__((ext_vector_type(4)));

#define GLDS16(gp, lp) __builtin_amdgcn_global_load_lds( \
    (const __attribute__((address_space(1))) void*)(gp), \
    (__attribute__((address_space(3))) void*)(lp), 16, 0, 0)

__global__ __launch_bounds__(256) void dhpm_prep(
    const float* __restrict__ Wu1, const float* __restrict__ Wv1, const float* __restrict__ Wf1,
    const float* __restrict__ Wu0, const float* __restrict__ bu0,
    const float* __restrict__ Wv0, const float* __restrict__ bv0,
    const float* __restrict__ Wf0, const float* __restrict__ bf0,
    char* __restrict__ ws)
{
    int id = blockIdx.x * blockDim.x + threadIdx.x;
    const int nW = 3 * NT * 16 * 116;   // 72384
    if (id < nW) {
        const int net = id / (NT*16*116);
        int e = id - net * (NT*16*116);
        const int nt  = e / (16*116);  e -= nt * (16*116);
        const int row = e / 116;
        const int k2  = e - row * 116;
        const int j   = nt*16 + row;
        const int k   = k2*2;
        const float* W = (net == 0) ? Wu1 : (net == 1) ? Wv1 : Wf1;
        f16x2 v; v[0] = (f16)0.f; v[1] = (f16)0.f;
        if (j < HID) {
            if (k     < HID) v[0] = (f16)W[j*HID + k];
            if (k + 1 < HID) v[1] = (f16)W[j*HID + k + 1];
        }
        *(f16x2*)(ws + net*106496 + nt*WCHUNK + row*464 + k2*4) = v;
        return;
    }
    id -= nW;
    if (id < 400) {
        const int net = id / HID;
        const int r   = id - net*HID;
        const float* W0 = net ? Wv0 : Wu0;
        const float* b0 = net ? bv0 : bu0;
        float4 c;
        c.x = W0[r*3+0]; c.y = W0[r*3+1]; c.z = W0[r*3+2]; c.w = b0[r];
        *(float4*)(ws + (net ? OFF_CV : OFF_CU) + r*16) = c;
        return;
    }
    id -= 400;
    if (id < HID) {
        const int i = id;
        float4 c0, c1, c2, c3;
        c0.x = Wf0[i*12+0];  c0.y = Wf0[i*12+1];  c0.z = Wf0[i*12+2];  c0.w = Wf0[i*12+3];
        c1.x = Wf0[i*12+4];  c1.y = Wf0[i*12+5];  c1.z = Wf0[i*12+6];  c1.w = Wf0[i*12+7];
        c2.x = Wf0[i*12+8];  c2.y = Wf0[i*12+9];  c2.z = Wf0[i*12+10]; c2.w = Wf0[i*12+11];
        c3.x = bf0[i]; c3.y = 0.f; c3.z = 0.f; c3.w = 0.f;
        char* p = ws + OFF_CF + i*64;
        *(float4*)(p)      = c0;
        *(float4*)(p + 16) = c1;
        *(float4*)(p + 32) = c2;
        *(float4*)(p + 48) = c3;
    }
}

__device__ __forceinline__ f32x4 mfma16(f16x8 a, f16x8 b, f32x4 c) {
    return __builtin_amdgcn_mfma_f32_16x16x32_f16(a, b, c, 0, 0, 0);
}

// g0 partials: p0=val, p1=xx, p2=yy.  g1 partials: p0=dx, p1=dy, p2=dt.
__device__ __forceinline__ void run_net(
    const float* __restrict__ inp, const char* __restrict__ ws,
    const int wOff, const int cstOff,
    const float* __restrict__ b1, const float* __restrict__ W2, const float b2s,
    const int cV, const int cXX, const int cYY,
    const int cX, const int cY, const int cT,
    char* __restrict__ Bb0, char* __restrict__ Bb1,
    float* __restrict__ exch, float* __restrict__ res,
    const int gp0, const int lane, const int w, const int q, const int g,
    const int jl, const int klo)
{
    const char* src = ws + wOff;

    // stage nt=0 -> Bb0 (one GLDS per thread; 8 waves cover 8 KB)
    GLDS16(src + w*1024 + lane*16, Bb0 + w*1024);

    // ---- A' fragments: 3 channels x 7 kt = 84 VGPR ----
    f16x8 aP[3][KT];
    {
        const float4* cst = (const float4*)(ws + cstOff);
        const int pt = gp0 + q*16 + jl;
        const float x = inp[pt*3+0], y = inp[pt*3+1], tt = inp[pt*3+2];
        #pragma unroll
        for (int kt = 0; kt < KT; ++kt) {
            f16x8 f0, f1, f2;
            #pragma unroll
            for (int e = 0; e < 8; ++e) {
                const int i = kt*32 + klo*8 + e;
                const float4 c = cst[(i < HID) ? i : 0];   // pad-k rows of B are 0
                const float z = fmaf(c.x, x, fmaf(c.y, y, fmaf(c.z, tt, c.w)));
                if (g == 0) {
                    const float s = __sinf(z);
                    f0[e] = (f16)s;
                    f1[e] = (f16)(-s * c.x * c.x);
                    f2[e] = (f16)(-s * c.y * c.y);
                } else {
                    const float cv = __cosf(z);
                    f0[e] = (f16)(cv * c.x);
                    f1[e] = (f16)(cv * c.y);
                    f2[e] = (f16)(cv * c.z);
                }
            }
            aP[0][kt] = f0; aP[1][kt] = f1; aP[2][kt] = f2;
        }
    }

    float p0a[4] = {0,0,0,0}, p1a[4] = {0,0,0,0}, p2a[4] = {0,0,0,0};

    float* E0  = exch;              // wc   (g0 -> g1)
    float* Edx = exch + 16*ELD;     // Ydx  (g1 -> g0)
    float* Edy = exch + 32*ELD;     // Ydy  (g1 -> g0)

    __syncthreads();   // Bb0 landed; prior-phase exch reads done

    for (int nt = 0; nt < NT; ++nt) {
        const char* Bcur = (nt & 1) ? Bb1 : Bb0;
        char*       Bnxt = (nt & 1) ? Bb0 : Bb1;
        if (nt + 1 < NT)
            GLDS16(src + (nt+1)*WCHUNK + w*1024 + lane*16, Bnxt + w*1024);

        f32x4 acc0 = {0,0,0,0}, acc1 = {0,0,0,0}, acc2 = {0,0,0,0};
        const f16* BH = (const f16*)Bcur;
        #pragma unroll
        for (int kt = 0; kt < KT; ++kt) {
            const f16x8 b = *(const f16x8*)&BH[jl*BLDK + kt*32 + klo*8];
            acc0 = mfma16(aP[0][kt], b, acc0);
            acc1 = mfma16(aP[1][kt], b, acc1);
            acc2 = mfma16(aP[2][kt], b, acc2);
        }

        const int j = nt*16 + jl;
        const float b1j = (j < HID) ? b1[j] : 0.f;
        const float w2j = (j < HID) ? W2[j] : 0.f;   // zeros pad-j contributions
        const int pcol = q*16 + klo*4;
        float wcr[4], wsr[4];
        if (g == 0) {
            f32x4 wc4;
            #pragma unroll
            for (int r = 0; r < 4; ++r) {
                float s1, c1;
                __sincosf(acc0[r] + b1j, &s1, &c1);
                wcr[r] = w2j * c1;
                wsr[r] = w2j * s1;
                p0a[r] += wsr[r];               // val
                wc4[r] = wcr[r];
            }
            *(f32x4*)&E0[jl*ELD + pcol] = wc4;
        } else {
            *(f32x4*)&Edx[jl*ELD + pcol] = acc0;
            *(f32x4*)&Edy[jl*ELD + pcol] = acc1;
        }
        __syncthreads();   // exchange visible

        if (g == 0) {
            const f32x4 ydx = *(const f32x4*)&Edx[jl*ELD + pcol];
            const f32x4 ydy = *(const f32x4*)&Edy[jl*ELD + pcol];
            #pragma unroll
            for (int r = 0; r < 4; ++r) {
                p1a[r] = fmaf(wcr[r], acc1[r], fmaf(-wsr[r]*ydx[r], ydx[r], p1a[r])); // xx
                p2a[r] = fmaf(wcr[r], acc2[r], fmaf(-wsr[r]*ydy[r], ydy[r], p2a[r])); // yy
            }
        } else {
            const f32x4 wc4 = *(const f32x4*)&E0[jl*ELD + pcol];
            #pragma unroll
            for (int r = 0; r < 4; ++r) {
                p0a[r] = fmaf(wc4[r], acc0[r], p0a[r]);   // dx
                p1a[r] = fmaf(wc4[r], acc1[r], p1a[r]);   // dy
                p2a[r] = fmaf(wc4[r], acc2[r], p2a[r]);   // dt
            }
        }
        __syncthreads();   // exch reads done; Bnxt landed
    }

    // butterfly over the 16 j-lanes
    #pragma unroll
    for (int d = 1; d < 16; d <<= 1)
        #pragma unroll
        for (int r = 0; r < 4; ++r) {
            p0a[r] += __shfl_xor(p0a[r], d);
            p1a[r] += __shfl_xor(p1a[r], d);
            p2a[r] += __shfl_xor(p2a[r], d);
        }
    if (jl == 0) {
        const int p0 = q*16 + klo*4;
        f32x4 v;
        if (g == 0) {
            #pragma unroll
            for (int r = 0; r < 4; ++r) v[r] = p0a[r] + b2s;
            *(f32x4*)&res[cV*72 + p0] = v;
            #pragma unroll
            for (int r = 0; r < 4; ++r) v[r] = p1a[r];
            *(f32x4*)&res[cXX*72 + p0] = v;
            #pragma unroll
            for (int r = 0; r < 4; ++r) v[r] = p2a[r];
            *(f32x4*)&res[cYY*72 + p0] = v;
        } else {
            #pragma unroll
            for (int r = 0; r < 4; ++r) v[r] = p0a[r];
            *(f32x4*)&res[cX*72 + p0] = v;
            #pragma unroll
            for (int r = 0; r < 4; ++r) v[r] = p1a[r];
            *(f32x4*)&res[cY*72 + p0] = v;
            #pragma unroll
            for (int r = 0; r < 4; ++r) v[r] = p2a[r];
            *(f32x4*)&res[cT*72 + p0] = v;
        }
    }
}

__global__ __launch_bounds__(NTH, 2) void dhpm_main(
    const float* __restrict__ inp, const char* __restrict__ ws,
    const float* __restrict__ bu1, const float* __restrict__ Wu2, const float* __restrict__ bu2,
    const float* __restrict__ bv1, const float* __restrict__ Wv2, const float* __restrict__ bv2,
    const float* __restrict__ bf1, const float* __restrict__ Wf2, const float* __restrict__ bf2,
    float* __restrict__ out, const int Np)
{
    __shared__ __align__(16) char LDS[37824];
    char*  Bb0  = LDS;                        // 8 KB
    char*  Bb1  = LDS + 8192;                 // 8 KB
    float* exch = (float*)(LDS + 16384);      // 3*16*68*4 = 13056 B
    f16*   Af   = (f16*)LDS;                  // f-net: [64][232] f16 = 29696 B (aliases the above)
    float* res  = (float*)(LDS + 29696);      // [14][72] f32 = 4032 B
    float* pfb  = (float*)(LDS + 33728);      // [8][2][64] f32 = 4096 B

    const int t = threadIdx.x;
    const int lane = t & 63;
    const int w = __builtin_amdgcn_readfirstlane(t >> 6);
    const int q = w & 3, g = w >> 2;
    const int jl = lane & 15, klo = lane >> 4;
    const int gp0 = blockIdx.x * 64;

    run_net(inp, ws, OFF_WU, OFF_CU, bu1, Wu2, bu2[0], 0, 5, 7, 4, 6, 2,
            Bb0, Bb1, exch, res, gp0, lane, w, q, g, jl, klo);
    run_net(inp, ws, OFF_WV, OFF_CV, bv1, Wv2, bv2[0], 1, 9, 11, 8, 10, 3,
            Bb0, Bb1, exch, res, gp0, lane, w, q, g, jl, klo);

    __syncthreads();   // res cols 0..11 complete; Bb/exch region free

    // ======================= f-net =======================
    // j-split: wave w owns nt = w (all) and nt = w+8 (w<5). Wf1 fragments
    // register-resident from L2; shared A_f tile in LDS.
    const int nown = (w < 5) ? 2 : 1;
    f16x8 bF[2][KT];
    #pragma unroll
    for (int ont = 0; ont < 2; ++ont)
        if (ont < nown) {
            const int nt = w + ont*8;
            #pragma unroll
            for (int kt = 0; kt < KT; ++kt)
                bF[ont][kt] = *(const f16x8*)(ws + OFF_WF + nt*WCHUNK
                                              + jl*464 + kt*64 + klo*16);
        }

    if (w < 4) {   // waves 0..3 build A_f for pts w*16+jl
        const int p = w*16 + jl;
        float fv[12];
        #pragma unroll
        for (int k = 0; k < 12; ++k) fv[k] = res[k*72 + p];
        const float4* cf = (const float4*)(ws + OFF_CF);
        #pragma unroll
        for (int kt = 0; kt < KT; ++kt) {
            f16x8 f;
            #pragma unroll
            for (int e = 0; e < 8; ++e) {
                const int i = kt*32 + klo*8 + e;
                const int ic = (i < HID) ? i : 0;
                const float4 c0 = cf[ic*4+0];
                const float4 c1 = cf[ic*4+1];
                const float4 c2 = cf[ic*4+2];
                const float4 c3 = cf[ic*4+3];
                float z = c3.x;
                z = fmaf(c0.x, fv[0], z);  z = fmaf(c0.y, fv[1], z);
                z = fmaf(c0.z, fv[2], z);  z = fmaf(c0.w, fv[3], z);
                z = fmaf(c1.x, fv[4], z);  z = fmaf(c1.y, fv[5], z);
                z = fmaf(c1.z, fv[6], z);  z = fmaf(c1.w, fv[7], z);
                z = fmaf(c2.x, fv[8], z);  z = fmaf(c2.y, fv[9], z);
                z = fmaf(c2.z, fv[10], z); z = fmaf(c2.w, fv[11], z);
                f[e] = (f16)__sinf(z);
            }
            *(f16x8*)((char*)Af + p*464 + kt*64 + klo*16) = f;
        }
    }
    __syncthreads();   // A_f complete

    f32x4 accF[2][4];
    #pragma unroll
    for (int ont = 0; ont < 2; ++ont)
        #pragma unroll
        for (int mt = 0; mt < 4; ++mt) { f32x4 z = {0,0,0,0}; accF[ont][mt] = z; }

    #pragma unroll
    for (int kt = 0; kt < KT; ++kt)
        #pragma unroll
        for (int mt = 0; mt < 4; ++mt) {
            const f16x8 a = *(const f16x8*)((const char*)Af
                                + (mt*16 + jl)*464 + kt*64 + klo*16);
            #pragma unroll
            for (int ont = 0; ont < 2; ++ont)
                if (ont < nown)
                    accF[ont][mt] = mfma16(a, bF[ont][kt], accF[ont][mt]);
        }

    float pf0[4][4], pf1[4][4];
    #pragma unroll
    for (int mt = 0; mt < 4; ++mt)
        #pragma unroll
        for (int r = 0; r < 4; ++r) { pf0[mt][r] = 0.f; pf1[mt][r] = 0.f; }

    #pragma unroll
    for (int ont = 0; ont < 2; ++ont)
        if (ont < nown) {
            const int j = (w + ont*8)*16 + jl;
            const float bj = (j < HID) ? bf1[j] : 0.f;
            const float wa = (j < HID) ? Wf2[j] : 0.f;
            const float wb = (j < HID) ? Wf2[HID + j] : 0.f;
            #pragma unroll
            for (int mt = 0; mt < 4; ++mt)
                #pragma unroll
                for (int r = 0; r < 4; ++r) {
                    const float h = __sinf(accF[ont][mt][r] + bj);
                    pf0[mt][r] = fmaf(wa, h, pf0[mt][r]);
                    pf1[mt][r] = fmaf(wb, h, pf1[mt][r]);
                }
        }

    #pragma unroll
    for (int d = 1; d < 16; d <<= 1)
        #pragma unroll
        for (int mt = 0; mt < 4; ++mt)
            #pragma unroll
            for (int r = 0; r < 4; ++r) {
                pf0[mt][r] += __shfl_xor(pf0[mt][r], d);
                pf1[mt][r] += __shfl_xor(pf1[mt][r], d);
            }
    if (jl == 0) {
        #pragma unroll
        for (int mt = 0; mt < 4; ++mt) {
            f32x4 v0, v1;
            #pragma unroll
            for (int r = 0; r < 4; ++r) { v0[r] = pf0[mt][r]; v1[r] = pf1[mt][r]; }
            *(f32x4*)&pfb[w*128 + 0*64 + mt*16 + klo*4] = v0;
            *(f32x4*)&pfb[w*128 + 1*64 + mt*16 + klo*4] = v1;
        }
    }
    __syncthreads();
    if (t < 128) {
        const int pt = t & 63, ch = t >> 6;
        float s = bf2[ch];
        #pragma unroll
        for (int ww = 0; ww < 8; ++ww) s += pfb[ww*128 + ch*64 + pt];
        res[(12 + ch)*72 + pt] = s;
    }
    __syncthreads();

    // coalesced final store
    for (int e = t; e < 14*64; e += NTH) {
        const int c = e >> 6, p = e & 63;
        out[(size_t)c*Np + gp0 + p] = res[c*72 + p];
    }
}

extern "C" void kernel_launch(void* const* d_in, const int* in_sizes, int n_in,
                              void* d_out, int out_size, void* d_ws, size_t ws_size,
                              hipStream_t stream) {
    const float* inp = (const float*)d_in[0];
    const float* Wu0 = (const float*)d_in[1];  const float* bu0 = (const float*)d_in[2];
    const float* Wu1 = (const float*)d_in[3];  const float* bu1 = (const float*)d_in[4];
    const float* Wu2 = (const float*)d_in[5];  const float* bu2 = (const float*)d_in[6];
    const float* Wv0 = (const float*)d_in[7];  const float* bv0 = (const float*)d_in[8];
    const float* Wv1 = (const float*)d_in[9];  const float* bv1 = (const float*)d_in[10];
    const float* Wv2 = (const float*)d_in[11]; const float* bv2 = (const float*)d_in[12];
    const float* Wf0 = (const float*)d_in[13]; const float* bf0 = (const float*)d_in[14];
    const float* Wf1 = (const float*)d_in[15]; const float* bf1 = (const float*)d_in[16];
    const float* Wf2 = (const float*)d_in[17]; const float* bf2 = (const float*)d_in[18];
    float* out = (float*)d_out;
    char* ws = (char*)d_ws;   // ~340 KB used

    const int Np = in_sizes[0] / 3;  // 262144

    const int nTot = 3*NT*16*116 + 400 + HID;  // 72984
    dhpm_prep<<<(nTot + 255) / 256, 256, 0, stream>>>(
        Wu1, Wv1, Wf1, Wu0, bu0, Wv0, bv0, Wf0, bf0, ws);
    dhpm_main<<<Np / 64, NTH, 0, stream>>>(
        inp, ws, bu1, Wu2, bu2, bv1, Wv2, bv2, bf1, Wf2, bf2, out, Np);
}